// Round 5
// baseline (293.356 us; speedup 1.0000x reference)
//
#include <hip/hip_runtime.h>
#include <stdint.h>

#define BATCH 128
#define NN 512
#define BINS 100
#define WORDS 8    // 512 bits / 64, natural order: bit b of word m = column 64m+b
#define WPAD 9     // +1 u64 pad -> benign LDS bank aliasing
#define ECAP 6144  // upper-tri edge capacity; expected ~2615, huge margin
#define PACK_BLOCKS 2048

// ---------------- Kernel A — pack fp32 adjacency -> bitsets (natural order) -
// Lane L of a wave handles row 4u+(L>>4), column word (L&15): loads its own
// contiguous 128 B (8 float4, kept in flight via sched_barrier) and builds a
// u32 mask per-lane (no cross-lane ballot). Store: 64 lanes -> 256 B
// contiguous. 2048 blocks x 4 waves = 32 waves/graph, 4 row-quads each.
__global__ __launch_bounds__(256) void k_pack(
    const float* __restrict__ adj1, const float* __restrict__ adj2,
    unsigned int* __restrict__ bits32 /* [256][512][16] */)
{
    const int lane = threadIdx.x & 63;
    const int wid  = blockIdx.x * 4 + (threadIdx.x >> 6);  // 0..8191
    const int gb   = wid >> 5;                             // 32 waves/graph
    const int lw   = wid & 31;
    const float* __restrict__ gp =
        (gb < BATCH ? adj1 : adj2) + (size_t)(gb & (BATCH - 1)) * NN * NN;
    const int rsub = lane >> 4;   // row within quad
    const int cw   = lane & 15;   // u32 word within row

    for (int u = lw; u < NN / 4; u += 32) {
        int r = 4 * u + rsub;
        const float4* __restrict__ p4 =
            (const float4*)(gp + (size_t)r * NN + cw * 32);
        float4 f[8];
        #pragma unroll
        for (int k = 0; k < 8; ++k) f[k] = p4[k];
#if __has_builtin(__builtin_amdgcn_sched_barrier)
        __builtin_amdgcn_sched_barrier(0);  // keep all 8 loads in flight
#endif
        unsigned m = 0u;
        #pragma unroll
        for (int k = 0; k < 8; ++k) {
            m |= (f[k].x != 0.0f ? 1u : 0u) << (4 * k + 0);
            m |= (f[k].y != 0.0f ? 1u : 0u) << (4 * k + 1);
            m |= (f[k].z != 0.0f ? 1u : 0u) << (4 * k + 2);
            m |= (f[k].w != 0.0f ? 1u : 0u) << (4 * k + 3);
        }
        bits32[((size_t)gb * NN + r) * 16 + cw] = m;  // 256 B/wave, coalesced
    }
}

// ---------------- Kernel B — triangles + histogram --------------------------
__global__ __launch_bounds__(1024) void k_tri_hist(
    const unsigned long long* __restrict__ bits_g,
    float* __restrict__ hist /* [2*BATCH][BINS] */)
{
    __shared__ unsigned long long bits[NN][WPAD];
    __shared__ unsigned int edges[ECAP];
    __shared__ int tri2[NN];
    __shared__ int histI[BINS];
    __shared__ int ecnt;

    const int gb  = blockIdx.x;
    const int tid = threadIdx.x;
    const int lane = tid & 63;
    const unsigned long long* src = bits_g + (size_t)gb * NN * WORDS;

    if (tid < BINS) histI[tid] = 0;
    if (tid < NN)   tri2[tid]  = 0;
    if (tid == 0)   ecnt = 0;

    #pragma unroll
    for (int g = tid; g < NN * WORDS; g += 1024)
        bits[g >> 3][g & 7] = src[g];
    __syncthreads();

    // Phase 2a: upper-tri edge list (j > r). Natural mapping: j = 64m + L.
    for (int p = tid; p < NN * WORDS; p += 1024) {
        int r = p >> 3;
        int m = p & 7;
        unsigned long long w = bits[r][m];
        int base = m << 6;
        int sh = r - base + 1;  // keep bits L with base+L > r  <=>  L >= sh
        unsigned long long wm =
            (sh <= 0) ? w : (sh >= 64 ? 0ull : (w & (~0ull << sh)));
        int cnt = __popcll(wm);

        int x = cnt;
        #pragma unroll
        for (int off = 1; off < 64; off <<= 1) {
            int y = __shfl_up(x, off, 64);
            if (lane >= off) x += y;
        }
        int excl = x - cnt;
        int bs = 0;
        if (lane == 63) bs = atomicAdd(&ecnt, x);
        bs = __shfl(bs, 63, 64);

        int idx = bs + excl;
        while (wm) {
            int L = __builtin_ctzll(wm);
            wm &= wm - 1;
            int j = base + L;
            if (idx < ECAP) edges[idx] = ((unsigned)r << 10) | (unsigned)j;
            ++idx;
        }
    }
    __syncthreads();

    // Phase 2b: edge-parallel intersection counts.
    const int ne = ecnt < ECAP ? ecnt : ECAP;
    for (int e = tid; e < ne; e += 1024) {
        unsigned ed = edges[e];
        int i = ed >> 10;
        int j = ed & 1023;
        int acc = 0;
        #pragma unroll
        for (int w = 0; w < WORDS; ++w)
            acc += __popcll(bits[i][w] & bits[j][w]);
        atomicAdd(&tri2[i], acc);
        atomicAdd(&tri2[j], acc);
    }
    __syncthreads();

    // Phase 2c: clustering coeff + histogram.
    if (tid < NN) {
        int deg = 0;
        #pragma unroll
        for (int w = 0; w < WORDS; ++w) deg += __popcll(bits[tid][w]);
        float t2    = (float)tri2[tid];
        float degf  = (float)deg;
        float denom = degf * (degf - 1.0f);
        float c = denom > 0.0f ? t2 / denom : 0.0f;  // exact int/int in fp32
        int idx = (int)(c * 100.0f);                  // trunc == astype(int32)
        idx = idx < 0 ? 0 : (idx > BINS - 1 ? BINS - 1 : idx);
        atomicAdd(&histI[idx], 1);
    }
    __syncthreads();

    if (tid < BINS) hist[(size_t)gb * BINS + tid] = (float)histI[tid];
}

// ---------------- MMD kernels ----------------------------------------------
__global__ __launch_bounds__(256) void k_mmd_partial(
    const float* __restrict__ hist, float* __restrict__ partials)
{
    int p = blockIdx.x * 256 + threadIdx.x;
    int t   = p >> 14;          // 0:XX 1:YY 2:XY
    int rem = p & 16383;
    int i = rem >> 7;
    int j = rem & 127;
    const float4* x4;
    const float4* y4;
    float w;
    if (t == 0)      { x4 = (const float4*)(hist + (size_t)i * BINS);           y4 = (const float4*)(hist + (size_t)j * BINS);           w =  1.0f; }
    else if (t == 1) { x4 = (const float4*)(hist + (size_t)(BATCH + i) * BINS); y4 = (const float4*)(hist + (size_t)(BATCH + j) * BINS); w =  1.0f; }
    else             { x4 = (const float4*)(hist + (size_t)i * BINS);           y4 = (const float4*)(hist + (size_t)(BATCH + j) * BINS); w = -2.0f; }
    float sq = 0.0f;
    #pragma unroll
    for (int k = 0; k < BINS / 4; ++k) {
        float4 a = x4[k];
        float4 b = y4[k];
        float d0 = a.x - b.x, d1 = a.y - b.y, d2 = a.z - b.z, d3 = a.w - b.w;
        sq += d0 * d0 + d1 * d1 + d2 * d2 + d3 * d3;
    }
    float local = w * expf(-0.5f * sq);  // sigma=1

    __shared__ float red[256];
    red[threadIdx.x] = local;
    __syncthreads();
    for (int s = 128; s >= 1; s >>= 1) {
        if (threadIdx.x < s) red[threadIdx.x] += red[threadIdx.x + s];
        __syncthreads();
    }
    if (threadIdx.x == 0) partials[blockIdx.x] = red[0];
}

__global__ __launch_bounds__(64) void k_mmd_final(
    const float* __restrict__ partials, float* __restrict__ out, int nparts)
{
    int lane = threadIdx.x;
    float v = 0.0f;
    for (int p = lane; p < nparts; p += 64) v += partials[p];
    #pragma unroll
    for (int off = 32; off >= 1; off >>= 1) v += __shfl_xor(v, off, 64);
    if (lane == 0) out[0] = v * (1.0f / (float)(BATCH * BATCH));
}

extern "C" void kernel_launch(void* const* d_in, const int* in_sizes, int n_in,
                              void* d_out, int out_size, void* d_ws, size_t ws_size,
                              hipStream_t stream) {
    const float* a1 = (const float*)d_in[0];
    const float* a2 = (const float*)d_in[1];
    float* out = (float*)d_out;

    const size_t bits_bytes = (size_t)2 * BATCH * NN * WORDS * 8;  // 8 MB
    const size_t hist_bytes = (size_t)2 * BATCH * BINS * 4;        // 102.4 KB

    unsigned int* bits32 = (unsigned int*)d_ws;
    float* hist     = (float*)((char*)d_ws + bits_bytes);
    float* partials = (float*)((char*)d_ws + bits_bytes + hist_bytes);

    hipLaunchKernelGGL(k_pack, dim3(PACK_BLOCKS), dim3(256), 0, stream,
                       a1, a2, bits32);
    hipLaunchKernelGGL(k_tri_hist, dim3(2 * BATCH), dim3(1024), 0, stream,
                       (const unsigned long long*)bits32, hist);
    hipLaunchKernelGGL(k_mmd_partial, dim3(192), dim3(256), 0, stream,
                       hist, partials);
    hipLaunchKernelGGL(k_mmd_final, dim3(1), dim3(64), 0, stream,
                       partials, out, 192);
}

// Round 6
// 283.654 us; speedup vs baseline: 1.0342x; 1.0342x over previous
//
#include <hip/hip_runtime.h>
#include <stdint.h>

#define BATCH 128
#define NN 512
#define BINS 100
#define WORDS 8    // 512 bits / 64, natural order: bit b of word m = column 64m+b
#define WPAD 9     // +1 u64 pad -> benign LDS bank aliasing
#define ECAP 6144  // upper-tri edge capacity; expected ~2615, huge margin

#define PK_BLOCKS 512         // 2 blocks/CU (64 KB LDS each)
#define CHUNK_FLOATS 16384    // 64 KB = 32 rows
#define NCHUNKS 4096          // 256 MB / 64 KB

// ---------------- Kernel A — pack via async global->LDS DMA -----------------
// Per chunk (64 KB = 32 rows of one graph): 64 x 1KB global_load_lds issues
// (16 per wave, no destination VGPRs -> all in flight), barrier-drain, then
// each thread builds two u32 masks (32 floats each) from LDS with a
// lane-rotated word order (bank = word index -> rotation gives 2-way
// aliasing = free [m136]) and stores coalesced.
__global__ __launch_bounds__(256) void k_pack(
    const float* __restrict__ adj1, const float* __restrict__ adj2,
    unsigned int* __restrict__ bits32 /* [256][512][16] */)
{
    __shared__ float lds[CHUNK_FLOATS];  // 64 KB
    const int tid  = threadIdx.x;
    const int lane = tid & 63;
    const int wave = tid >> 6;  // 0..3

    for (int c = blockIdx.x; c < NCHUNKS; c += PK_BLOCKS) {
        const int gb = c >> 4;             // 16 chunks per graph
        const int r0 = (c & 15) * 32;      // first row of chunk
        const float* __restrict__ gp =
            (gb < BATCH ? adj1 : adj2) + (size_t)(gb & (BATCH - 1)) * NN * NN
            + (size_t)r0 * NN;
        const float* gsrc = gp + lane * 4;  // lane's 16B within each 1KB unit

        // Stage 64 KB: wave w issues units w*16 .. w*16+15 back-to-back.
        #pragma unroll
        for (int i = 0; i < 16; ++i) {
            const int off = (wave * 16 + i) * 256;  // floats per 1KB unit
            __builtin_amdgcn_global_load_lds(
                (const __attribute__((address_space(1))) unsigned int*)(gsrc + off),
                (__attribute__((address_space(3))) unsigned int*)&lds[off],
                16, 0, 0);
        }
        __syncthreads();  // drains vmcnt -> LDS valid

        // Consume: 512 masks/chunk; thread t does masks t and t+256.
        #pragma unroll
        for (int half = 0; half < 2; ++half) {
            const int M = tid + half * 256;
            const unsigned int* mp = (const unsigned int*)&lds[M * 32];
            unsigned int m = 0u;
            #pragma unroll
            for (int k = 0; k < 32; ++k) {
                const int w = (k + lane) & 31;  // rotated: bank w, 2 lanes/bank
                m |= (mp[w] ? 1u : 0u) << w;    // 1.0f pattern nonzero as u32
            }
            const int rl = M >> 4;    // row within chunk
            const int wd = M & 15;    // u32 word within row
            bits32[((size_t)gb * NN + r0 + rl) * 16 + wd] = m;
        }
        __syncthreads();  // protect LDS before next round's DMA
    }
}

// ---------------- Kernel B — triangles + histogram --------------------------
__global__ __launch_bounds__(1024) void k_tri_hist(
    const unsigned long long* __restrict__ bits_g,
    float* __restrict__ hist /* [2*BATCH][BINS] */)
{
    __shared__ unsigned long long bits[NN][WPAD];
    __shared__ unsigned int edges[ECAP];
    __shared__ int tri2[NN];
    __shared__ int histI[BINS];
    __shared__ int ecnt;

    const int gb  = blockIdx.x;
    const int tid = threadIdx.x;
    const int lane = tid & 63;
    const unsigned long long* src = bits_g + (size_t)gb * NN * WORDS;

    if (tid < BINS) histI[tid] = 0;
    if (tid < NN)   tri2[tid]  = 0;
    if (tid == 0)   ecnt = 0;

    #pragma unroll
    for (int g = tid; g < NN * WORDS; g += 1024)
        bits[g >> 3][g & 7] = src[g];
    __syncthreads();

    // Phase 2a: upper-tri edge list (j > r). Natural mapping: j = 64m + L.
    for (int p = tid; p < NN * WORDS; p += 1024) {
        int r = p >> 3;
        int m = p & 7;
        unsigned long long w = bits[r][m];
        int base = m << 6;
        int sh = r - base + 1;  // keep bits L with base+L > r  <=>  L >= sh
        unsigned long long wm =
            (sh <= 0) ? w : (sh >= 64 ? 0ull : (w & (~0ull << sh)));
        int cnt = __popcll(wm);

        int x = cnt;
        #pragma unroll
        for (int off = 1; off < 64; off <<= 1) {
            int y = __shfl_up(x, off, 64);
            if (lane >= off) x += y;
        }
        int excl = x - cnt;
        int bs = 0;
        if (lane == 63) bs = atomicAdd(&ecnt, x);
        bs = __shfl(bs, 63, 64);

        int idx = bs + excl;
        while (wm) {
            int L = __builtin_ctzll(wm);
            wm &= wm - 1;
            int j = base + L;
            if (idx < ECAP) edges[idx] = ((unsigned)r << 10) | (unsigned)j;
            ++idx;
        }
    }
    __syncthreads();

    // Phase 2b: edge-parallel intersection counts.
    const int ne = ecnt < ECAP ? ecnt : ECAP;
    for (int e = tid; e < ne; e += 1024) {
        unsigned ed = edges[e];
        int i = ed >> 10;
        int j = ed & 1023;
        int acc = 0;
        #pragma unroll
        for (int w = 0; w < WORDS; ++w)
            acc += __popcll(bits[i][w] & bits[j][w]);
        atomicAdd(&tri2[i], acc);
        atomicAdd(&tri2[j], acc);
    }
    __syncthreads();

    // Phase 2c: clustering coeff + histogram.
    if (tid < NN) {
        int deg = 0;
        #pragma unroll
        for (int w = 0; w < WORDS; ++w) deg += __popcll(bits[tid][w]);
        float t2    = (float)tri2[tid];
        float degf  = (float)deg;
        float denom = degf * (degf - 1.0f);
        float c = denom > 0.0f ? t2 / denom : 0.0f;  // exact int/int in fp32
        int idx = (int)(c * 100.0f);                  // trunc == astype(int32)
        idx = idx < 0 ? 0 : (idx > BINS - 1 ? BINS - 1 : idx);
        atomicAdd(&histI[idx], 1);
    }
    __syncthreads();

    if (tid < BINS) hist[(size_t)gb * BINS + tid] = (float)histI[tid];
}

// ---------------- MMD kernels ----------------------------------------------
__global__ __launch_bounds__(256) void k_mmd_partial(
    const float* __restrict__ hist, float* __restrict__ partials)
{
    int p = blockIdx.x * 256 + threadIdx.x;
    int t   = p >> 14;          // 0:XX 1:YY 2:XY
    int rem = p & 16383;
    int i = rem >> 7;
    int j = rem & 127;
    const float4* x4;
    const float4* y4;
    float w;
    if (t == 0)      { x4 = (const float4*)(hist + (size_t)i * BINS);           y4 = (const float4*)(hist + (size_t)j * BINS);           w =  1.0f; }
    else if (t == 1) { x4 = (const float4*)(hist + (size_t)(BATCH + i) * BINS); y4 = (const float4*)(hist + (size_t)(BATCH + j) * BINS); w =  1.0f; }
    else             { x4 = (const float4*)(hist + (size_t)i * BINS);           y4 = (const float4*)(hist + (size_t)(BATCH + j) * BINS); w = -2.0f; }
    float sq = 0.0f;
    #pragma unroll
    for (int k = 0; k < BINS / 4; ++k) {
        float4 a = x4[k];
        float4 b = y4[k];
        float d0 = a.x - b.x, d1 = a.y - b.y, d2 = a.z - b.z, d3 = a.w - b.w;
        sq += d0 * d0 + d1 * d1 + d2 * d2 + d3 * d3;
    }
    float local = w * expf(-0.5f * sq);  // sigma=1

    __shared__ float red[256];
    red[threadIdx.x] = local;
    __syncthreads();
    for (int s = 128; s >= 1; s >>= 1) {
        if (threadIdx.x < s) red[threadIdx.x] += red[threadIdx.x + s];
        __syncthreads();
    }
    if (threadIdx.x == 0) partials[blockIdx.x] = red[0];
}

__global__ __launch_bounds__(64) void k_mmd_final(
    const float* __restrict__ partials, float* __restrict__ out, int nparts)
{
    int lane = threadIdx.x;
    float v = 0.0f;
    for (int p = lane; p < nparts; p += 64) v += partials[p];
    #pragma unroll
    for (int off = 32; off >= 1; off >>= 1) v += __shfl_xor(v, off, 64);
    if (lane == 0) out[0] = v * (1.0f / (float)(BATCH * BATCH));
}

extern "C" void kernel_launch(void* const* d_in, const int* in_sizes, int n_in,
                              void* d_out, int out_size, void* d_ws, size_t ws_size,
                              hipStream_t stream) {
    const float* a1 = (const float*)d_in[0];
    const float* a2 = (const float*)d_in[1];
    float* out = (float*)d_out;

    const size_t bits_bytes = (size_t)2 * BATCH * NN * WORDS * 8;  // 8 MB
    const size_t hist_bytes = (size_t)2 * BATCH * BINS * 4;        // 102.4 KB

    unsigned int* bits32 = (unsigned int*)d_ws;
    float* hist     = (float*)((char*)d_ws + bits_bytes);
    float* partials = (float*)((char*)d_ws + bits_bytes + hist_bytes);

    hipLaunchKernelGGL(k_pack, dim3(PK_BLOCKS), dim3(256), 0, stream,
                       a1, a2, bits32);
    hipLaunchKernelGGL(k_tri_hist, dim3(2 * BATCH), dim3(1024), 0, stream,
                       (const unsigned long long*)bits32, hist);
    hipLaunchKernelGGL(k_mmd_partial, dim3(192), dim3(256), 0, stream,
                       hist, partials);
    hipLaunchKernelGGL(k_mmd_final, dim3(1), dim3(64), 0, stream,
                       partials, out, 192);
}

// Round 7
// 255.880 us; speedup vs baseline: 1.1465x; 1.1085x over previous
//
#include <hip/hip_runtime.h>
#include <stdint.h>

#define BATCH 128
#define NN 512
#define BINS 100
#define WORDS 8    // 512 bits / 64; natural order: bit b of word m = column 64m+b
#define WPAD 9     // +1 u64 pad -> benign LDS bank aliasing
#define ECAP 6144  // upper-tri edge capacity; expected ~2615, huge margin

// spread 16 bits to stride-4 positions (bit i -> bit 4i)
__device__ __forceinline__ unsigned long long spread4(unsigned long long x) {
    x = (x | (x << 24)) & 0x000000ff000000ffull;
    x = (x | (x << 12)) & 0x000f000f000f000full;
    x = (x | (x <<  6)) & 0x0303030303030303ull;
    x = (x | (x <<  3)) & 0x1111111111111111ull;
    return x;
}

// One block per graph. Phase 1 reads ONLY the upper triangle (64-col-block
// granularity: row r reads cols [64*(r/64), 512) — 0.5625x bytes, 1 masked
// wave-load per row), ballot-packs, and SWAR-unpermutes to natural bit order.
// Phase 1b rebuilds the lower triangle by symmetric 64x64 bit-transposes
// (6-step shfl_xor). Phases 2a-2c (edge list / triangles / histogram) as R6.
__global__ __launch_bounds__(1024) void k_cluster_hist(
    const float* __restrict__ adj1, const float* __restrict__ adj2,
    float* __restrict__ hist /* [2*BATCH][BINS] */)
{
    __shared__ unsigned long long bits[NN][WPAD];   // 36,864 B
    __shared__ unsigned int edges[ECAP];            // 24,576 B
    __shared__ int tri2[NN];                        //  2,048 B
    __shared__ int histI[BINS];
    __shared__ int ecnt;

    const int gb = blockIdx.x;  // 0..255
    const float* __restrict__ gp =
        (gb < BATCH ? adj1 : adj2) + (size_t)(gb & (BATCH - 1)) * NN * NN;

    const int tid  = threadIdx.x;
    const int lane = tid & 63;
    const int wave = tid >> 6;  // 0..15

    if (tid < BINS) histI[tid] = 0;
    if (tid < NN)   tri2[tid]  = 0;
    if (tid == 0)   ecnt = 0;

    // ---- Phase 1: upper-triangle read + natural-order pack.
    for (int r = wave; r < NN; r += 16) {
        const int br = r >> 6;       // diagonal 64-col block
        const int nb = 8 - br;       // words to read
        const int c0 = br << 6;
        float4 v = make_float4(0.f, 0.f, 0.f, 0.f);
        if (lane < 16 * nb)
            v = *(const float4*)(gp + (size_t)r * NN + c0 + 4 * lane);
        // ballot q bit L = A[r][c0 + 4L + q]
        unsigned long long b0 = __ballot(v.x != 0.0f);
        unsigned long long b1 = __ballot(v.y != 0.0f);
        unsigned long long b2 = __ballot(v.z != 0.0f);
        unsigned long long b3 = __ballot(v.w != 0.0f);
        // lane d < nb assembles natural word m = br + d from span word s = d:
        // bit 4a+q of word = ballot_q bit 16s+a
        if (lane < nb) {
            const int sh = 16 * lane;
            unsigned long long w =
                (spread4((b0 >> sh) & 0xFFFFull) << 0) |
                (spread4((b1 >> sh) & 0xFFFFull) << 1) |
                (spread4((b2 >> sh) & 0xFFFFull) << 2) |
                (spread4((b3 >> sh) & 0xFFFFull) << 3);
            bits[r][br + lane] = w;
        }
    }
    __syncthreads();

    // ---- Phase 1b: fill lower triangle by symmetry.
    // Pair p -> (bi, bj), bi in [1,8), bj < bi, p = bi(bi-1)/2 + bj (28 pairs).
    for (int p = wave; p < 28; p += 16) {
        int bi = 1;
        while (bi * (bi + 1) / 2 <= p) ++bi;   // largest bi with T(bi)<=p
        const int bj = p - bi * (bi - 1) / 2;
        // x at lane i: rows block bj, col-word bi (upper, present)
        unsigned long long x = bits[(bj << 6) + lane][bi];
        // 64x64 bit transpose across the wave
        const unsigned long long M[6] = {
            0x5555555555555555ull, 0x3333333333333333ull,
            0x0f0f0f0f0f0f0f0full, 0x00ff00ff00ff00ffull,
            0x0000ffff0000ffffull, 0x00000000ffffffffull };
        #pragma unroll
        for (int s = 0; s < 6; ++s) {
            const int k = 1 << s;
            unsigned long long y = __shfl_xor((long long)x, k, 64);
            if ((lane & k) == 0) x = (x &  M[s]) | ((y &  M[s]) << k);
            else                 x = (x & ~M[s]) | ((y & ~M[s]) >> k);
        }
        bits[(bi << 6) + lane][bj] = x;  // A symmetric -> transpose = lower blk
    }
    __syncthreads();

    // ---- Phase 2a: upper-tri edge list (j > r); j = 64m + L.
    for (int p = tid; p < NN * WORDS; p += 1024) {
        int r = p >> 3;
        int m = p & 7;
        unsigned long long w = bits[r][m];
        int base = m << 6;
        int sh = r - base + 1;  // keep bits L with base+L > r
        unsigned long long wm =
            (sh <= 0) ? w : (sh >= 64 ? 0ull : (w & (~0ull << sh)));
        int cnt = __popcll(wm);

        int x = cnt;
        #pragma unroll
        for (int off = 1; off < 64; off <<= 1) {
            int y = __shfl_up(x, off, 64);
            if (lane >= off) x += y;
        }
        int excl = x - cnt;
        int bs = 0;
        if (lane == 63) bs = atomicAdd(&ecnt, x);
        bs = __shfl(bs, 63, 64);

        int idx = bs + excl;
        while (wm) {
            int L = __builtin_ctzll(wm);
            wm &= wm - 1;
            int j = base + L;
            if (idx < ECAP) edges[idx] = ((unsigned)r << 10) | (unsigned)j;
            ++idx;
        }
    }
    __syncthreads();

    // ---- Phase 2b: edge-parallel intersection counts.
    const int ne = ecnt < ECAP ? ecnt : ECAP;
    for (int e = tid; e < ne; e += 1024) {
        unsigned ed = edges[e];
        int i = ed >> 10;
        int j = ed & 1023;
        int acc = 0;
        #pragma unroll
        for (int w = 0; w < WORDS; ++w)
            acc += __popcll(bits[i][w] & bits[j][w]);
        atomicAdd(&tri2[i], acc);
        atomicAdd(&tri2[j], acc);
    }
    __syncthreads();

    // ---- Phase 2c: clustering coeff + histogram.
    if (tid < NN) {
        int deg = 0;
        #pragma unroll
        for (int w = 0; w < WORDS; ++w) deg += __popcll(bits[tid][w]);
        float t2    = (float)tri2[tid];
        float degf  = (float)deg;
        float denom = degf * (degf - 1.0f);
        float c = denom > 0.0f ? t2 / denom : 0.0f;  // exact int/int in fp32
        int idx = (int)(c * 100.0f);                  // trunc == astype(int32)
        idx = idx < 0 ? 0 : (idx > BINS - 1 ? BINS - 1 : idx);
        atomicAdd(&histI[idx], 1);
    }
    __syncthreads();

    if (tid < BINS) hist[(size_t)gb * BINS + tid] = (float)histI[tid];
}

// ---------------- MMD kernels ----------------------------------------------
__global__ __launch_bounds__(256) void k_mmd_partial(
    const float* __restrict__ hist, float* __restrict__ partials)
{
    int p = blockIdx.x * 256 + threadIdx.x;
    int t   = p >> 14;          // 0:XX 1:YY 2:XY
    int rem = p & 16383;
    int i = rem >> 7;
    int j = rem & 127;
    const float4* x4;
    const float4* y4;
    float w;
    if (t == 0)      { x4 = (const float4*)(hist + (size_t)i * BINS);           y4 = (const float4*)(hist + (size_t)j * BINS);           w =  1.0f; }
    else if (t == 1) { x4 = (const float4*)(hist + (size_t)(BATCH + i) * BINS); y4 = (const float4*)(hist + (size_t)(BATCH + j) * BINS); w =  1.0f; }
    else             { x4 = (const float4*)(hist + (size_t)i * BINS);           y4 = (const float4*)(hist + (size_t)(BATCH + j) * BINS); w = -2.0f; }
    float sq = 0.0f;
    #pragma unroll
    for (int k = 0; k < BINS / 4; ++k) {
        float4 a = x4[k];
        float4 b = y4[k];
        float d0 = a.x - b.x, d1 = a.y - b.y, d2 = a.z - b.z, d3 = a.w - b.w;
        sq += d0 * d0 + d1 * d1 + d2 * d2 + d3 * d3;
    }
    float local = w * expf(-0.5f * sq);  // sigma=1

    __shared__ float red[256];
    red[threadIdx.x] = local;
    __syncthreads();
    for (int s = 128; s >= 1; s >>= 1) {
        if (threadIdx.x < s) red[threadIdx.x] += red[threadIdx.x + s];
        __syncthreads();
    }
    if (threadIdx.x == 0) partials[blockIdx.x] = red[0];
}

__global__ __launch_bounds__(64) void k_mmd_final(
    const float* __restrict__ partials, float* __restrict__ out, int nparts)
{
    int lane = threadIdx.x;
    float v = 0.0f;
    for (int p = lane; p < nparts; p += 64) v += partials[p];
    #pragma unroll
    for (int off = 32; off >= 1; off >>= 1) v += __shfl_xor(v, off, 64);
    if (lane == 0) out[0] = v * (1.0f / (float)(BATCH * BATCH));
}

extern "C" void kernel_launch(void* const* d_in, const int* in_sizes, int n_in,
                              void* d_out, int out_size, void* d_ws, size_t ws_size,
                              hipStream_t stream) {
    const float* a1 = (const float*)d_in[0];
    const float* a2 = (const float*)d_in[1];
    float* out = (float*)d_out;

    const size_t hist_bytes = (size_t)2 * BATCH * BINS * 4;  // 102.4 KB
    float* hist     = (float*)d_ws;
    float* partials = (float*)((char*)d_ws + hist_bytes);

    hipLaunchKernelGGL(k_cluster_hist, dim3(2 * BATCH), dim3(1024), 0, stream,
                       a1, a2, hist);
    hipLaunchKernelGGL(k_mmd_partial, dim3(192), dim3(256), 0, stream,
                       hist, partials);
    hipLaunchKernelGGL(k_mmd_final, dim3(1), dim3(64), 0, stream,
                       partials, out, 192);
}